// Round 4
// baseline (397.457 us; speedup 1.0000x reference)
//
#include <hip/hip_runtime.h>
#include <math.h>

#define TT 256
#define HH 128
#define QT 4

__device__ __forceinline__ void enc6(float t, float e[6]) {
  float x = 6.2831853071795864769f * t;
  float a0 = x / 86400.0f, a1 = x / 604800.0f, a2 = x / 2592000.0f;
  e[0] = sinf(a0); e[1] = sinf(a1); e[2] = sinf(a2);
  e[3] = cosf(a0); e[4] = cosf(a1); e[5] = cosf(a2);
}

__global__ __launch_bounds__(128) void embed_kernel(
    const int* __restrict__ log_seqs, const float* __restrict__ time_seq,
    const float* __restrict__ item_emb, const float* __restrict__ time_proj,
    float* __restrict__ seqs, float* __restrict__ sc6) {
  int row = blockIdx.x;
  int h = threadIdx.x;
  float t = time_seq[row];
  float e[6]; enc6(t, e);
  int idx = log_seqs[row];
  const float* tp = time_proj + h * 6;
  float val = item_emb[(size_t)idx * HH + h] * 11.313708498984761f; // sqrt(128)
  val += e[0]*tp[0] + e[1]*tp[1] + e[2]*tp[2] + e[3]*tp[3] + e[4]*tp[4] + e[5]*tp[5];
  seqs[(size_t)row * HH + h] = (idx != 0) ? val : 0.0f;
  if (h < 6) sc6[row * 6 + h] = e[h];
}

// which = blockIdx.x>>8: 0=Q (with LN, writes QN too), 1=K(+absK, TRANSPOSED out), 2=V(+absV).
__global__ __launch_bounds__(128) void qkv_fused(
    const float* __restrict__ S,
    const float* __restrict__ Wq, const float* __restrict__ bq,
    const float* __restrict__ Wk, const float* __restrict__ bk,
    const float* __restrict__ Wv, const float* __restrict__ bv,
    const float* __restrict__ lng, const float* __restrict__ lnb,
    const float* __restrict__ absK, const float* __restrict__ absV,
    float* __restrict__ QN, float* __restrict__ QB,
    float* __restrict__ KT, float* __restrict__ VB) {
  int which = blockIdx.x >> 8;
  int m0 = (blockIdx.x & 255) * 8;
  int n = threadIdx.x;
  __shared__ float At[8][132];
  __shared__ float mu[8], rs[8];
  #pragma unroll
  for (int r = 0; r < 8; ++r) At[r][n] = S[(size_t)(m0 + r) * HH + n];
  __syncthreads();
  if (which == 0) {
    if (n < 64) {
      int r = n >> 3, sg = n & 7;
      float s = 0.f;
      #pragma unroll
      for (int i = 0; i < 16; ++i) s += At[r][sg * 16 + i];
      s += __shfl_xor(s, 1); s += __shfl_xor(s, 2); s += __shfl_xor(s, 4);
      if (sg == 0) mu[r] = s * (1.0f / HH);
    }
    __syncthreads();
    if (n < 64) {
      int r = n >> 3, sg = n & 7;
      float mm = mu[r], s = 0.f;
      #pragma unroll
      for (int i = 0; i < 16; ++i) { float d = At[r][sg*16+i] - mm; s += d * d; }
      s += __shfl_xor(s, 1); s += __shfl_xor(s, 2); s += __shfl_xor(s, 4);
      if (sg == 0) rs[r] = rsqrtf(s * (1.0f / HH) + 1e-8f);
    }
    __syncthreads();
    float gg = lng[n], bb = lnb[n];
    #pragma unroll
    for (int r = 0; r < 8; ++r) {
      float v = (At[r][n] - mu[r]) * rs[r] * gg + bb;
      At[r][n] = v;
      QN[(size_t)(m0 + r) * HH + n] = v;
    }
    __syncthreads();
  }
  const float* W    = which == 0 ? Wq : which == 1 ? Wk : Wv;
  const float* bias = which == 0 ? bq : which == 1 ? bk : bv;
  const float* addP = which == 1 ? absK : which == 2 ? absV : nullptr;
  float* dst        = which == 0 ? QB : which == 1 ? KT : VB;
  float acc[8];
  #pragma unroll
  for (int r = 0; r < 8; ++r) acc[r] = 0.f;
  const float* wr = W + (size_t)n * HH;
  for (int d = 0; d < HH; d += 4) {
    float4 w = *(const float4*)(wr + d);
    #pragma unroll
    for (int r = 0; r < 8; ++r) {
      float4 a = *(const float4*)(&At[r][d]);
      acc[r] = fmaf(a.x, w.x, fmaf(a.y, w.y, fmaf(a.z, w.z, fmaf(a.w, w.w, acc[r]))));
    }
  }
  float bn = bias[n];
  #pragma unroll
  for (int r = 0; r < 8; ++r) {
    int m = m0 + r;
    float v = acc[r] + bn;
    if (addP) v += addP[(size_t)(m & 255) * HH + n];
    if (which == 1) {
      // KT[((b*2+h)*64 + d)*256 + t]
      int bb2 = m >> 8, t = m & 255, hh2 = n >> 6, dd = n & 63;
      dst[(((size_t)(bb2 * 2 + hh2) * 64) + dd) * 256 + t] = v;
    } else {
      dst[(size_t)m * HH + n] = v;
    }
  }
}

// PK[((b*2+h)*256+q)*257 + i] = 0.125 * sum_d QB[b,q,h*64+d] * tKe[i, h*64+d]
__global__ __launch_bounds__(256) void pk_gemm(
    const float* __restrict__ QB, const float* __restrict__ tKe,
    float* __restrict__ PK) {
  int blk = blockIdx.x;          // 256 blocks: (b*2+h)*16 + qt
  int qt = blk & 15;
  int bh = blk >> 4;
  int h = bh & 1;
  int b = bh >> 1;
  int q0 = qt * 16;
  int hoff = h * 64;
  int tid = threadIdx.x;
  __shared__ float Qs[16][64];
  for (int idx = tid; idx < 16 * 64; idx += 256) {
    int q = idx >> 6, d = idx & 63;
    Qs[q][d] = QB[((size_t)(b * TT + q0 + q)) * HH + hoff + d];
  }
  __syncthreads();
  for (int i = tid; i < 257; i += 256) {
    const float* tp = tKe + (size_t)i * HH + hoff;
    float acc[16];
    #pragma unroll
    for (int q = 0; q < 16; ++q) acc[q] = 0.f;
    for (int d = 0; d < 64; d += 4) {
      float4 t4 = *(const float4*)(tp + d);
      #pragma unroll
      for (int q = 0; q < 16; ++q) {
        float4 qv = *(const float4*)(&Qs[q][d]);
        acc[q] = fmaf(qv.x, t4.x, fmaf(qv.y, t4.y, fmaf(qv.z, t4.z, fmaf(qv.w, t4.w, acc[q]))));
      }
    }
    float* dstp = PK + ((size_t)(bh * TT + q0)) * 257 + i;
    #pragma unroll
    for (int q = 0; q < 16; ++q) dstp[(size_t)q * 257] = acc[q] * 0.125f;
  }
}

// grid: b(8) x h(2) x qt(64); 256 thr = 4 q-waves. PK lookup replaces tK gather;
// tVe read from L2 (wave-uniform row -> coalesced).
__global__ __launch_bounds__(256) void attn_fused(
    const float* __restrict__ QB, const float* __restrict__ KT,
    const float* __restrict__ VB, const float* __restrict__ QN,
    const int* __restrict__ log_seqs, const int* __restrict__ tmat,
    const float* __restrict__ sc6, const float* __restrict__ PK,
    const float* __restrict__ tVe, const float* __restrict__ lambdas,
    float* __restrict__ out) {
  int blk = blockIdx.x;
  int qt = blk & 63;
  int h = (blk >> 6) & 1;
  int b = blk >> 7;
  int q0 = qt << 2;
  int hoff = h << 6;
  int tid = threadIdx.x;

  __shared__ float Qt[QT][64];
  __shared__ float Pp[QT][256];
  __shared__ float PKs[QT][260];
  __shared__ unsigned short tmq[QT][256];
  __shared__ float sk6[256 * 6];
  __shared__ float sq6[QT * 6];
  __shared__ unsigned char kmask[256];

  { int q = tid >> 6, d = tid & 63;
    Qt[q][d] = QB[((size_t)(b * TT + q0 + q)) * HH + hoff + d]; }
  for (int idx = tid; idx < 256 * 6; idx += 256)
    sk6[idx] = sc6[(size_t)b * (256 * 6) + idx];
  if (tid < QT * 6) sq6[tid] = sc6[((size_t)(b * TT + q0)) * 6 + tid];
  #pragma unroll
  for (int q = 0; q < QT; ++q)
    for (int i = tid; i < 257; i += 256)
      PKs[q][i] = PK[((size_t)((b * 2 + h) * TT + q0 + q)) * 257 + i];
  for (int idx = tid; idx < QT * 256; idx += 256) {
    int q = idx >> 8, k = idx & 255;
    tmq[q][k] = (unsigned short)tmat[((size_t)(b * TT + q0 + q)) * TT + k];
  }
  kmask[tid] = (log_seqs[b * TT + tid] == 0) ? 1 : 0;
  __syncthreads();

  int q = tid >> 6;
  int lane = tid & 63;
  int qg = q0 + q;
  float4 qreg[16];
  #pragma unroll
  for (int i = 0; i < 16; ++i) qreg[i] = *(const float4*)(&Qt[q][i << 2]);
  float l0 = lambdas[0], l1 = lambdas[1], l2 = lambdas[2];
  float sA = sq6[q*6+0], sB = sq6[q*6+1], sC = sq6[q*6+2];
  float cA = sq6[q*6+3], cB = sq6[q*6+4], cC = sq6[q*6+5];
  const float* ktb = KT + ((size_t)((b * 2 + h) * 64)) * 256;  // [d][t]
  float sarr[4];
  #pragma unroll
  for (int j = 0; j < 4; ++j) {
    int k = lane + (j << 6);
    float sv = -1e9f;
    if (k <= qg && kmask[k] == 0) {
      float acc = 0.f;
      #pragma unroll
      for (int d4 = 0; d4 < 16; ++d4) {
        float4 qv = qreg[d4];
        const float* kp = ktb + (size_t)(d4 << 2) * 256 + k;
        acc = fmaf(qv.x, kp[0],   acc);
        acc = fmaf(qv.y, kp[256], acc);
        acc = fmaf(qv.z, kp[512], acc);
        acc = fmaf(qv.w, kp[768], acc);
      }
      int tm = tmq[q][k];
      const float* s6 = &sk6[k * 6];
      float pb = l0 * (sA * s6[0] + cA * s6[3])
               + l1 * (sB * s6[1] + cB * s6[4])
               + l2 * (sC * s6[2] + cC * s6[5]);
      sv = acc + PKs[q][tm] + pb;   // acc already includes 1/8 via... no: PK has 1/8; K-dot needs it
      sv = (acc * 0.125f) + PKs[q][tm] + pb;
    }
    sarr[j] = sv;
  }
  float m = fmaxf(fmaxf(sarr[0], sarr[1]), fmaxf(sarr[2], sarr[3]));
  #pragma unroll
  for (int o = 32; o > 0; o >>= 1) m = fmaxf(m, __shfl_xor(m, o));
  float p0 = __expf(sarr[0] - m), p1 = __expf(sarr[1] - m),
        p2 = __expf(sarr[2] - m), p3 = __expf(sarr[3] - m);
  float l = p0 + p1 + p2 + p3;
  #pragma unroll
  for (int o = 32; o > 0; o >>= 1) l += __shfl_xor(l, o);
  float inv = 1.0f / l;
  Pp[q][lane]       = p0 * inv;
  Pp[q][lane + 64]  = p1 * inv;
  Pp[q][lane + 128] = p2 * inv;
  Pp[q][lane + 192] = p3 * inv;
  __syncthreads();

  // masked keys have p==0 exactly unless whole row masked (m==-1e9): then all 256.
  int kend = (m < -5e8f) ? 256 : (qg + 1);
  float oacc = 0.f;
  const float* vb  = VB + ((size_t)(b * TT)) * HH + hoff + lane;
  const float* tvb = tVe + hoff + lane;
  #pragma unroll 4
  for (int k = 0; k < kend; ++k) {
    float pk = Pp[q][k];
    int tm = tmq[q][k];
    oacc = fmaf(pk, vb[(size_t)k * HH] + tvb[(size_t)tm * HH], oacc);
  }
  size_t obase = ((size_t)(b * TT + qg)) * HH + hoff + lane;
  out[obase] = QN[obase] + oacc;
}

// LN + relu(x@W1^T+b1)@W2^T + b2 + x, keep-mask. 4-row tiles.
__global__ __launch_bounds__(128) void ffn_fused(
    const float* __restrict__ S, const float* __restrict__ W1, const float* __restrict__ b1,
    const float* __restrict__ W2, const float* __restrict__ b2,
    const float* __restrict__ lng, const float* __restrict__ lnb,
    const int* __restrict__ log_seqs, float* __restrict__ outS) {
  int m0 = blockIdx.x * 4;
  int n = threadIdx.x;
  __shared__ float Xt[4][132];
  __shared__ float Ht[4][132];
  __shared__ float mu[4], rs[4];
  #pragma unroll
  for (int r = 0; r < 4; ++r) Xt[r][n] = S[(size_t)(m0 + r) * HH + n];
  __syncthreads();
  if (n < 32) {
    int r = n >> 3, sg = n & 7;
    float s = 0.f;
    #pragma unroll
    for (int i = 0; i < 16; ++i) s += Xt[r][sg * 16 + i];
    s += __shfl_xor(s, 1); s += __shfl_xor(s, 2); s += __shfl_xor(s, 4);
    if (sg == 0) mu[r] = s * (1.0f / HH);
  }
  __syncthreads();
  if (n < 32) {
    int r = n >> 3, sg = n & 7;
    float mm = mu[r], s = 0.f;
    #pragma unroll
    for (int i = 0; i < 16; ++i) { float d = Xt[r][sg*16+i] - mm; s += d * d; }
    s += __shfl_xor(s, 1); s += __shfl_xor(s, 2); s += __shfl_xor(s, 4);
    if (sg == 0) rs[r] = rsqrtf(s * (1.0f / HH) + 1e-8f);
  }
  __syncthreads();
  float gg = lng[n], bb = lnb[n];
  #pragma unroll
  for (int r = 0; r < 4; ++r) Xt[r][n] = (Xt[r][n] - mu[r]) * rs[r] * gg + bb;
  __syncthreads();
  float acc[4] = {0.f, 0.f, 0.f, 0.f};
  const float* wr = W1 + (size_t)n * HH;
  for (int d = 0; d < HH; d += 4) {
    float4 w = *(const float4*)(wr + d);
    #pragma unroll
    for (int r = 0; r < 4; ++r) {
      float4 a = *(const float4*)(&Xt[r][d]);
      acc[r] = fmaf(a.x, w.x, fmaf(a.y, w.y, fmaf(a.z, w.z, fmaf(a.w, w.w, acc[r]))));
    }
  }
  float b1n = b1[n];
  #pragma unroll
  for (int r = 0; r < 4; ++r) Ht[r][n] = fmaxf(acc[r] + b1n, 0.f);
  __syncthreads();
  float acc2[4] = {0.f, 0.f, 0.f, 0.f};
  wr = W2 + (size_t)n * HH;
  for (int d = 0; d < HH; d += 4) {
    float4 w = *(const float4*)(wr + d);
    #pragma unroll
    for (int r = 0; r < 4; ++r) {
      float4 a = *(const float4*)(&Ht[r][d]);
      acc2[r] = fmaf(a.x, w.x, fmaf(a.y, w.y, fmaf(a.z, w.z, fmaf(a.w, w.w, acc2[r]))));
    }
  }
  float b2n = b2[n];
  #pragma unroll
  for (int r = 0; r < 4; ++r) {
    int mrow = m0 + r;
    float v = acc2[r] + b2n + Xt[r][n];
    if (log_seqs[mrow] == 0) v = 0.f;
    outS[(size_t)mrow * HH + n] = v;
  }
}

__global__ __launch_bounds__(128) void hper_kernel(
    const float* __restrict__ target_t, const float* __restrict__ time_proj,
    const float* __restrict__ pred_W, const float* __restrict__ fus_W1,
    const float* __restrict__ fus_b1, float* __restrict__ hp1) {
  int b = blockIdx.x, hth = threadIdx.x;
  __shared__ float te[HH], hp[HH];
  float e[6]; enc6(target_t[b], e);
  const float* tp = time_proj + hth * 6;
  te[hth] = e[0]*tp[0]+e[1]*tp[1]+e[2]*tp[2]+e[3]*tp[3]+e[4]*tp[4]+e[5]*tp[5];
  __syncthreads();
  float u = 0.f;
  const float* pw = pred_W + (size_t)hth * HH;
  for (int d = 0; d < HH; ++d) u += te[d] * pw[d];
  hp[hth] = u;
  __syncthreads();
  float w = fus_b1[hth];
  const float* f1 = fus_W1 + (size_t)hth * 256 + 128;
  for (int d = 0; d < HH; ++d) w += hp[d] * f1[d];
  hp1[b * HH + hth] = w;
}

// last LN + gelu(L@fus_W1[:, :128]^T + hp1) @ fus_W2^T + fus_b2 -> logits. 4-row tiles.
__global__ __launch_bounds__(128) void final_fused(
    const float* __restrict__ S, const float* __restrict__ lng, const float* __restrict__ lnb,
    const float* __restrict__ fus_W1, const float* __restrict__ HP1,
    const float* __restrict__ fus_W2, const float* __restrict__ fus_b2,
    const float* __restrict__ item_emb, const int* __restrict__ pos,
    const int* __restrict__ neg, float* __restrict__ out) {
  int m0 = blockIdx.x * 4;
  int bidx = m0 >> 8;
  int n = threadIdx.x;
  __shared__ float Xt[4][132];
  __shared__ float Ht[4][132];
  __shared__ float Ft[4][132];
  __shared__ float mu[4], rs[4];
  #pragma unroll
  for (int r = 0; r < 4; ++r) Xt[r][n] = S[(size_t)(m0 + r) * HH + n];
  __syncthreads();
  if (n < 32) {
    int r = n >> 3, sg = n & 7;
    float s = 0.f;
    #pragma unroll
    for (int i = 0; i < 16; ++i) s += Xt[r][sg * 16 + i];
    s += __shfl_xor(s, 1); s += __shfl_xor(s, 2); s += __shfl_xor(s, 4);
    if (sg == 0) mu[r] = s * (1.0f / HH);
  }
  __syncthreads();
  if (n < 32) {
    int r = n >> 3, sg = n & 7;
    float mm = mu[r], s = 0.f;
    #pragma unroll
    for (int i = 0; i < 16; ++i) { float d = Xt[r][sg*16+i] - mm; s += d * d; }
    s += __shfl_xor(s, 1); s += __shfl_xor(s, 2); s += __shfl_xor(s, 4);
    if (sg == 0) rs[r] = rsqrtf(s * (1.0f / HH) + 1e-8f);
  }
  __syncthreads();
  float gg = lng[n], bb = lnb[n];
  #pragma unroll
  for (int r = 0; r < 4; ++r) Xt[r][n] = (Xt[r][n] - mu[r]) * rs[r] * gg + bb;
  __syncthreads();
  float acc[4] = {0.f, 0.f, 0.f, 0.f};
  const float* wr = fus_W1 + (size_t)n * 256;
  for (int d = 0; d < HH; d += 4) {
    float4 w = *(const float4*)(wr + d);
    #pragma unroll
    for (int r = 0; r < 4; ++r) {
      float4 a = *(const float4*)(&Xt[r][d]);
      acc[r] = fmaf(a.x, w.x, fmaf(a.y, w.y, fmaf(a.z, w.z, fmaf(a.w, w.w, acc[r]))));
    }
  }
  float hp = HP1[bidx * HH + n];
  #pragma unroll
  for (int r = 0; r < 4; ++r) {
    float v = acc[r] + hp;
    Ht[r][n] = 0.5f * v * (1.0f + erff(v * 0.70710678118654752f));
  }
  __syncthreads();
  float acc2[4] = {0.f, 0.f, 0.f, 0.f};
  wr = fus_W2 + (size_t)n * HH;
  for (int d = 0; d < HH; d += 4) {
    float4 w = *(const float4*)(wr + d);
    #pragma unroll
    for (int r = 0; r < 4; ++r) {
      float4 a = *(const float4*)(&Ht[r][d]);
      acc2[r] = fmaf(a.x, w.x, fmaf(a.y, w.y, fmaf(a.z, w.z, fmaf(a.w, w.w, acc2[r]))));
    }
  }
  float b2n = fus_b2[n];
  #pragma unroll
  for (int r = 0; r < 4; ++r) Ft[r][n] = acc2[r] + b2n;
  __syncthreads();
  if (n < 64) {
    int task = n >> 3;     // 0..7: r = task&3, which = task>>2
    int sg = n & 7;
    int r = task & 3;
    int w = task >> 2;
    int mrow = m0 + r;
    int idx = (w == 0) ? pos[mrow] : neg[mrow];
    const float* ie = item_emb + (size_t)idx * HH;
    float s = 0.f;
    #pragma unroll
    for (int i = 0; i < 16; ++i) s += Ft[r][sg * 16 + i] * ie[sg * 16 + i];
    s += __shfl_xor(s, 1); s += __shfl_xor(s, 2); s += __shfl_xor(s, 4);
    if (sg == 0) out[w * 2048 + mrow] = s;
  }
}

extern "C" void kernel_launch(void* const* d_in, const int* in_sizes, int n_in,
                              void* d_out, int out_size, void* d_ws, size_t ws_size,
                              hipStream_t stream) {
  const int*   log_seqs   = (const int*)d_in[0];
  const int*   tmat       = (const int*)d_in[1];
  const float* time_seq   = (const float*)d_in[2];
  const int*   pos_seqs   = (const int*)d_in[3];
  const int*   neg_seqs   = (const int*)d_in[4];
  const float* target_t   = (const float*)d_in[5];
  const float* item_emb   = (const float*)d_in[6];
  const float* abs_pos_K  = (const float*)d_in[7];
  const float* abs_pos_V  = (const float*)d_in[8];
  const float* time_K_emb = (const float*)d_in[9];
  const float* time_V_emb = (const float*)d_in[10];
  const float* Wq = (const float*)d_in[11];
  const float* bq = (const float*)d_in[12];
  const float* Wk = (const float*)d_in[13];
  const float* bk = (const float*)d_in[14];
  const float* Wv = (const float*)d_in[15];
  const float* bv = (const float*)d_in[16];
  const float* attn_ln_g = (const float*)d_in[17];
  const float* attn_ln_b = (const float*)d_in[18];
  const float* fwd_ln_g = (const float*)d_in[19];
  const float* fwd_ln_b = (const float*)d_in[20];
  const float* w1 = (const float*)d_in[21];
  const float* b1 = (const float*)d_in[22];
  const float* w2 = (const float*)d_in[23];
  const float* b2 = (const float*)d_in[24];
  const float* last_ln_g = (const float*)d_in[25];
  const float* last_ln_b = (const float*)d_in[26];
  const float* time_proj = (const float*)d_in[27];
  const float* lambdas = (const float*)d_in[28];
  const float* pred_W = (const float*)d_in[29];
  const float* fus_W1 = (const float*)d_in[30];
  const float* fus_b1 = (const float*)d_in[31];
  const float* fus_W2 = (const float*)d_in[32];
  const float* fus_b2 = (const float*)d_in[33];
  (void)in_sizes; (void)n_in; (void)out_size; (void)ws_size;

  float* out = (float*)d_out;
  float* ws = (float*)d_ws;
  const int M = 8 * TT;  // 2048
  float* SC6  = ws;                 // M*6
  float* SEQS = SC6 + M * 6;
  float* QN   = SEQS + M * HH;
  float* QB   = QN + M * HH;
  float* KT   = QB + M * HH;        // [b][h][d][t]
  float* VB   = KT + M * HH;
  float* HP1  = VB + M * HH;        // 8*128
  float* PK   = HP1 + 8 * HH;       // 16*256*257 f32 = 4.21 MB

  embed_kernel<<<M, HH, 0, stream>>>(log_seqs, time_seq, item_emb, time_proj, SEQS, SC6);
  for (int l = 0; l < 2; ++l) {
    const size_t wo = (size_t)l * HH * HH;
    const size_t bo = (size_t)l * HH;
    qkv_fused<<<768, 128, 0, stream>>>(SEQS, Wq + wo, bq + bo, Wk + wo, bk + bo,
                                       Wv + wo, bv + bo, attn_ln_g + bo, attn_ln_b + bo,
                                       abs_pos_K, abs_pos_V, QN, QB, KT, VB);
    pk_gemm<<<256, 256, 0, stream>>>(QB, time_K_emb, PK);
    attn_fused<<<1024, 256, 0, stream>>>(QB, KT, VB, QN, log_seqs, tmat, SC6,
                                         PK, time_V_emb, lambdas, SEQS);
    ffn_fused<<<512, 128, 0, stream>>>(SEQS, w1 + wo, b1 + bo, w2 + wo, b2 + bo,
                                       fwd_ln_g + bo, fwd_ln_b + bo, log_seqs, SEQS);
  }
  hper_kernel<<<8, 128, 0, stream>>>(target_t, time_proj, pred_W, fus_W1, fus_b1, HP1);
  final_fused<<<512, 128, 0, stream>>>(SEQS, last_ln_g, last_ln_b, fus_W1, HP1,
                                       fus_W2, fus_b2, item_emb, pos_seqs, neg_seqs, out);
}

// Round 5
// 294.546 us; speedup vs baseline: 1.3494x; 1.3494x over previous
//
#include <hip/hip_runtime.h>
#include <math.h>

#define TT 256
#define HH 128

__device__ __forceinline__ void enc6(float t, float e[6]) {
  float x = 6.2831853071795864769f * t;
  float a0 = x / 86400.0f, a1 = x / 604800.0f, a2 = x / 2592000.0f;
  e[0] = sinf(a0); e[1] = sinf(a1); e[2] = sinf(a2);
  e[3] = cosf(a0); e[4] = cosf(a1); e[5] = cosf(a2);
}

__global__ __launch_bounds__(128) void embed_kernel(
    const int* __restrict__ log_seqs, const float* __restrict__ time_seq,
    const float* __restrict__ item_emb, const float* __restrict__ time_proj,
    float* __restrict__ seqs, float* __restrict__ sc6) {
  int row = blockIdx.x;
  int h = threadIdx.x;
  float t = time_seq[row];
  float e[6]; enc6(t, e);
  int idx = log_seqs[row];
  const float* tp = time_proj + h * 6;
  float val = item_emb[(size_t)idx * HH + h] * 11.313708498984761f; // sqrt(128)
  val += e[0]*tp[0] + e[1]*tp[1] + e[2]*tp[2] + e[3]*tp[3] + e[4]*tp[4] + e[5]*tp[5];
  seqs[(size_t)row * HH + h] = (idx != 0) ? val : 0.0f;
  if (h < 6) sc6[row * 6 + h] = e[h];
}

// which = blockIdx.x>>8: 0=Q (with LN, writes QN too), 1=K(+absK, TRANSPOSED out), 2=V(+absV).
__global__ __launch_bounds__(128) void qkv_fused(
    const float* __restrict__ S,
    const float* __restrict__ Wq, const float* __restrict__ bq,
    const float* __restrict__ Wk, const float* __restrict__ bk,
    const float* __restrict__ Wv, const float* __restrict__ bv,
    const float* __restrict__ lng, const float* __restrict__ lnb,
    const float* __restrict__ absK, const float* __restrict__ absV,
    float* __restrict__ QN, float* __restrict__ QB,
    float* __restrict__ KT, float* __restrict__ VB) {
  int which = blockIdx.x >> 8;
  int m0 = (blockIdx.x & 255) * 8;
  int n = threadIdx.x;
  __shared__ float At[8][132];
  __shared__ float mu[8], rs[8];
  #pragma unroll
  for (int r = 0; r < 8; ++r) At[r][n] = S[(size_t)(m0 + r) * HH + n];
  __syncthreads();
  if (which == 0) {
    if (n < 64) {
      int r = n >> 3, sg = n & 7;
      float s = 0.f;
      #pragma unroll
      for (int i = 0; i < 16; ++i) s += At[r][sg * 16 + i];
      s += __shfl_xor(s, 1); s += __shfl_xor(s, 2); s += __shfl_xor(s, 4);
      if (sg == 0) mu[r] = s * (1.0f / HH);
    }
    __syncthreads();
    if (n < 64) {
      int r = n >> 3, sg = n & 7;
      float mm = mu[r], s = 0.f;
      #pragma unroll
      for (int i = 0; i < 16; ++i) { float d = At[r][sg*16+i] - mm; s += d * d; }
      s += __shfl_xor(s, 1); s += __shfl_xor(s, 2); s += __shfl_xor(s, 4);
      if (sg == 0) rs[r] = rsqrtf(s * (1.0f / HH) + 1e-8f);
    }
    __syncthreads();
    float gg = lng[n], bb = lnb[n];
    #pragma unroll
    for (int r = 0; r < 8; ++r) {
      float v = (At[r][n] - mu[r]) * rs[r] * gg + bb;
      At[r][n] = v;
      QN[(size_t)(m0 + r) * HH + n] = v;
    }
    __syncthreads();
  }
  const float* W    = which == 0 ? Wq : which == 1 ? Wk : Wv;
  const float* bias = which == 0 ? bq : which == 1 ? bk : bv;
  const float* addP = which == 1 ? absK : which == 2 ? absV : nullptr;
  float* dst        = which == 0 ? QB : which == 1 ? KT : VB;
  float acc[8];
  #pragma unroll
  for (int r = 0; r < 8; ++r) acc[r] = 0.f;
  const float* wr = W + (size_t)n * HH;
  for (int d = 0; d < HH; d += 4) {
    float4 w = *(const float4*)(wr + d);
    #pragma unroll
    for (int r = 0; r < 8; ++r) {
      float4 a = *(const float4*)(&At[r][d]);
      acc[r] = fmaf(a.x, w.x, fmaf(a.y, w.y, fmaf(a.z, w.z, fmaf(a.w, w.w, acc[r]))));
    }
  }
  float bn = bias[n];
  #pragma unroll
  for (int r = 0; r < 8; ++r) {
    int m = m0 + r;
    float v = acc[r] + bn;
    if (addP) v += addP[(size_t)(m & 255) * HH + n];
    if (which == 1) {
      // KT[((b*2+h)*64 + d)*256 + t]
      int bb2 = m >> 8, t = m & 255, hh2 = n >> 6, dd = n & 63;
      dst[(((size_t)(bb2 * 2 + hh2) * 64) + dd) * 256 + t] = v;
    } else {
      dst[(size_t)m * HH + n] = v;
    }
  }
}

// SCB[bh,q,k] = mask ? -1e9 : 0.125*(q . tKe[tm[b,q,k]]) + phase_bias(q,k)
// grid: 16 bh x 64 qtiles(4q) = 1024 blocks x 256 thr
__global__ __launch_bounds__(256) void pkscb_kernel(
    const float* __restrict__ QB, const float* __restrict__ tKe,
    const int* __restrict__ tmat, const int* __restrict__ log_seqs,
    const float* __restrict__ sc6, const float* __restrict__ lambdas,
    float* __restrict__ SCB) {
  int blk = blockIdx.x;
  int qt = blk & 63, bh = blk >> 6;
  int h = bh & 1, b = bh >> 1;
  int q0 = qt << 2, hoff = h << 6;
  int tid = threadIdx.x;
  __shared__ float Qs[4][64];
  __shared__ float PKl[4][264];
  __shared__ float sk6T[6][256];
  __shared__ float sq6[4][6];
  __shared__ unsigned char kmask[256];
  { int q = tid >> 6, d = tid & 63;
    Qs[q][d] = QB[((size_t)(b * TT + q0 + q)) * HH + hoff + d]; }
  for (int idx = tid; idx < 1536; idx += 256) {
    int kk = idx / 6, cc = idx - kk * 6;
    sk6T[cc][kk] = sc6[(size_t)b * 1536 + idx];
  }
  if (tid < 24) {
    int q = tid / 6, cc = tid - q * 6;
    sq6[q][cc] = sc6[((size_t)(b * TT + q0 + q)) * 6 + cc];
  }
  kmask[tid] = (log_seqs[b * TT + tid] == 0) ? 1 : 0;
  __syncthreads();
  for (int i = tid; i < 257; i += 256) {
    const float* tp = tKe + (size_t)i * HH + hoff;
    float a0 = 0.f, a1 = 0.f, a2 = 0.f, a3 = 0.f;
    #pragma unroll
    for (int d = 0; d < 64; d += 4) {
      float4 t4 = *(const float4*)(tp + d);
      float4 v0 = *(const float4*)(&Qs[0][d]);
      float4 v1 = *(const float4*)(&Qs[1][d]);
      float4 v2 = *(const float4*)(&Qs[2][d]);
      float4 v3 = *(const float4*)(&Qs[3][d]);
      a0 = fmaf(v0.x,t4.x,fmaf(v0.y,t4.y,fmaf(v0.z,t4.z,fmaf(v0.w,t4.w,a0))));
      a1 = fmaf(v1.x,t4.x,fmaf(v1.y,t4.y,fmaf(v1.z,t4.z,fmaf(v1.w,t4.w,a1))));
      a2 = fmaf(v2.x,t4.x,fmaf(v2.y,t4.y,fmaf(v2.z,t4.z,fmaf(v2.w,t4.w,a2))));
      a3 = fmaf(v3.x,t4.x,fmaf(v3.y,t4.y,fmaf(v3.z,t4.z,fmaf(v3.w,t4.w,a3))));
    }
    PKl[0][i] = a0 * 0.125f; PKl[1][i] = a1 * 0.125f;
    PKl[2][i] = a2 * 0.125f; PKl[3][i] = a3 * 0.125f;
  }
  __syncthreads();
  float l0 = lambdas[0], l1 = lambdas[1], l2 = lambdas[2];
  int k = tid;
  float c0 = sk6T[0][k], c1 = sk6T[1][k], c2 = sk6T[2][k],
        c3 = sk6T[3][k], c4 = sk6T[4][k], c5 = sk6T[5][k];
  int km = kmask[k];
  float* scbq = SCB + ((size_t)(bh * TT + q0)) * TT;
  #pragma unroll
  for (int qq = 0; qq < 4; ++qq) {
    int qg = q0 + qq;
    float pb = l0 * (sq6[qq][0] * c0 + sq6[qq][3] * c3)
             + l1 * (sq6[qq][1] * c1 + sq6[qq][4] * c4)
             + l2 * (sq6[qq][2] * c2 + sq6[qq][5] * c5);
    int tm = tmat[((size_t)(b * TT + qg)) * TT + k];
    float val = (k > qg || km) ? -1e9f : (PKl[qq][tm] + pb);
    scbq[(size_t)qq * TT + k] = val;
  }
}

// grid: 2048 blocks (XCD-swizzled), 256 thr, 2 q-rows per block.
// Score: wave w owns k in [64w,64w+64), lane=k -> coalesced SCB/KT reads.
// PV: k strided by 4 across waves, V row shared by both q.
__global__ __launch_bounds__(256) void attn_fused(
    const float* __restrict__ QB, const float* __restrict__ KT,
    const float* __restrict__ VB, const float* __restrict__ QN,
    const float* __restrict__ SCB, const int* __restrict__ tmat,
    const float* __restrict__ tVe, float* __restrict__ out) {
  int blk = blockIdx.x;
  blk = (blk & 7) * 256 + (blk >> 3);   // bijective XCD swizzle (2048 = 8*256)
  int qt = blk & 127;
  int h = (blk >> 7) & 1;
  int b = blk >> 8;
  int q0 = qt << 1;
  int hoff = h << 6;
  int tid = threadIdx.x;
  int w = tid >> 6, lane = tid & 63;

  __shared__ float Qt[2][64];
  __shared__ float Pp[2][256];
  __shared__ unsigned short tmq[2][256];
  __shared__ float part[4][2][64];
  __shared__ float red[16];

  if (tid < 128)
    Qt[tid >> 6][tid & 63] = QB[((size_t)(b * TT + q0 + (tid >> 6))) * HH + hoff + (tid & 63)];
  #pragma unroll
  for (int t = 0; t < 2; ++t) {
    int idx = tid + t * 256;
    int qq = idx >> 8, kk = idx & 255;
    tmq[qq][kk] = (unsigned short)tmat[((size_t)(b * TT + q0 + qq)) * TT + kk];
  }
  __syncthreads();

  int k = (w << 6) | lane;
  const float* scb0 = SCB + ((size_t)((b * 2 + h) * TT + q0)) * TT;
  float s0 = scb0[k];
  float s1 = scb0[TT + k];
  if ((w << 6) <= q0 + 1) {   // wave has at least one causally-valid key
    float a0 = 0.f, a1 = 0.f;
    const float* ktb = KT + ((size_t)((b * 2 + h) * 64)) * 256 + k;
    #pragma unroll
    for (int d4 = 0; d4 < 16; ++d4) {
      float4 qa = *(const float4*)(&Qt[0][d4 << 2]);
      float4 qb = *(const float4*)(&Qt[1][d4 << 2]);
      const float* kp = ktb + (size_t)(d4 << 2) * 256;
      float v0 = kp[0], v1 = kp[256], v2 = kp[512], v3 = kp[768];
      a0 = fmaf(qa.x, v0, fmaf(qa.y, v1, fmaf(qa.z, v2, fmaf(qa.w, v3, a0))));
      a1 = fmaf(qb.x, v0, fmaf(qb.y, v1, fmaf(qb.z, v2, fmaf(qb.w, v3, a1))));
    }
    if (s0 > -5e8f) s0 = fmaf(a0, 0.125f, s0);
    if (s1 > -5e8f) s1 = fmaf(a1, 0.125f, s1);
  }
  // softmax over 256 (wave-reduce + LDS combine)
  float m0 = s0, m1 = s1;
  #pragma unroll
  for (int o = 32; o > 0; o >>= 1) {
    m0 = fmaxf(m0, __shfl_xor(m0, o));
    m1 = fmaxf(m1, __shfl_xor(m1, o));
  }
  if (lane == 0) { red[w] = m0; red[4 + w] = m1; }
  __syncthreads();
  float gm0 = fmaxf(fmaxf(red[0], red[1]), fmaxf(red[2], red[3]));
  float gm1 = fmaxf(fmaxf(red[4], red[5]), fmaxf(red[6], red[7]));
  float p0 = (gm0 < -5e8f) ? 1.0f : __expf(s0 - gm0);  // fully-masked row -> uniform (ref)
  float p1 = (gm1 < -5e8f) ? 1.0f : __expf(s1 - gm1);
  float u0 = p0, u1 = p1;
  #pragma unroll
  for (int o = 32; o > 0; o >>= 1) {
    u0 += __shfl_xor(u0, o);
    u1 += __shfl_xor(u1, o);
  }
  if (lane == 0) { red[8 + w] = u0; red[12 + w] = u1; }
  __syncthreads();
  float inv0 = 1.0f / (red[8] + red[9] + red[10] + red[11]);
  float inv1 = 1.0f / (red[12] + red[13] + red[14] + red[15]);
  Pp[0][k] = p0 * inv0;
  Pp[1][k] = p1 * inv1;
  __syncthreads();

  int kend = (gm0 < -5e8f || gm1 < -5e8f) ? 256 : (q0 + 2);
  float o0 = 0.f, o1 = 0.f;
  const float* vbase = VB + ((size_t)(b * TT)) * HH + hoff + lane;
  const float* tvb   = tVe + hoff + lane;
  for (int kk = w; kk < kend; kk += 4) {
    float pa  = Pp[0][kk];
    float pb2 = Pp[1][kk];
    int ta = tmq[0][kk], tb = tmq[1][kk];
    float v  = vbase[(size_t)kk * HH];
    float t0 = tvb[(size_t)ta * HH];
    float t1 = tvb[(size_t)tb * HH];
    o0 = fmaf(pa,  v + t0, o0);
    o1 = fmaf(pb2, v + t1, o1);
  }
  part[w][0][lane] = o0;
  part[w][1][lane] = o1;
  __syncthreads();
  if (tid < 128) {
    int qq = tid >> 6, d = tid & 63;
    float o = part[0][qq][d] + part[1][qq][d] + part[2][qq][d] + part[3][qq][d];
    size_t ob = ((size_t)(b * TT + q0 + qq)) * HH + hoff + d;
    out[ob] = QN[ob] + o;
  }
}

// LN + relu(x@W1^T+b1)@W2^T + b2 + x, keep-mask. 4-row tiles.
__global__ __launch_bounds__(128) void ffn_fused(
    const float* __restrict__ S, const float* __restrict__ W1, const float* __restrict__ b1,
    const float* __restrict__ W2, const float* __restrict__ b2,
    const float* __restrict__ lng, const float* __restrict__ lnb,
    const int* __restrict__ log_seqs, float* __restrict__ outS) {
  int m0 = blockIdx.x * 4;
  int n = threadIdx.x;
  __shared__ float Xt[4][132];
  __shared__ float Ht[4][132];
  __shared__ float mu[4], rs[4];
  #pragma unroll
  for (int r = 0; r < 4; ++r) Xt[r][n] = S[(size_t)(m0 + r) * HH + n];
  __syncthreads();
  if (n < 32) {
    int r = n >> 3, sg = n & 7;
    float s = 0.f;
    #pragma unroll
    for (int i = 0; i < 16; ++i) s += Xt[r][sg * 16 + i];
    s += __shfl_xor(s, 1); s += __shfl_xor(s, 2); s += __shfl_xor(s, 4);
    if (sg == 0) mu[r] = s * (1.0f / HH);
  }
  __syncthreads();
  if (n < 32) {
    int r = n >> 3, sg = n & 7;
    float mm = mu[r], s = 0.f;
    #pragma unroll
    for (int i = 0; i < 16; ++i) { float d = Xt[r][sg*16+i] - mm; s += d * d; }
    s += __shfl_xor(s, 1); s += __shfl_xor(s, 2); s += __shfl_xor(s, 4);
    if (sg == 0) rs[r] = rsqrtf(s * (1.0f / HH) + 1e-8f);
  }
  __syncthreads();
  float gg = lng[n], bb = lnb[n];
  #pragma unroll
  for (int r = 0; r < 4; ++r) Xt[r][n] = (Xt[r][n] - mu[r]) * rs[r] * gg + bb;
  __syncthreads();
  float acc[4] = {0.f, 0.f, 0.f, 0.f};
  const float* wr = W1 + (size_t)n * HH;
  for (int d = 0; d < HH; d += 4) {
    float4 w = *(const float4*)(wr + d);
    #pragma unroll
    for (int r = 0; r < 4; ++r) {
      float4 a = *(const float4*)(&Xt[r][d]);
      acc[r] = fmaf(a.x, w.x, fmaf(a.y, w.y, fmaf(a.z, w.z, fmaf(a.w, w.w, acc[r]))));
    }
  }
  float b1n = b1[n];
  #pragma unroll
  for (int r = 0; r < 4; ++r) Ht[r][n] = fmaxf(acc[r] + b1n, 0.f);
  __syncthreads();
  float acc2[4] = {0.f, 0.f, 0.f, 0.f};
  wr = W2 + (size_t)n * HH;
  for (int d = 0; d < HH; d += 4) {
    float4 w = *(const float4*)(wr + d);
    #pragma unroll
    for (int r = 0; r < 4; ++r) {
      float4 a = *(const float4*)(&Ht[r][d]);
      acc2[r] = fmaf(a.x, w.x, fmaf(a.y, w.y, fmaf(a.z, w.z, fmaf(a.w, w.w, acc2[r]))));
    }
  }
  float b2n = b2[n];
  #pragma unroll
  for (int r = 0; r < 4; ++r) {
    int mrow = m0 + r;
    float v = acc2[r] + b2n + Xt[r][n];
    if (log_seqs[mrow] == 0) v = 0.f;
    outS[(size_t)mrow * HH + n] = v;
  }
}

__global__ __launch_bounds__(128) void hper_kernel(
    const float* __restrict__ target_t, const float* __restrict__ time_proj,
    const float* __restrict__ pred_W, const float* __restrict__ fus_W1,
    const float* __restrict__ fus_b1, float* __restrict__ hp1) {
  int b = blockIdx.x, hth = threadIdx.x;
  __shared__ float te[HH], hp[HH];
  float e[6]; enc6(target_t[b], e);
  const float* tp = time_proj + hth * 6;
  te[hth] = e[0]*tp[0]+e[1]*tp[1]+e[2]*tp[2]+e[3]*tp[3]+e[4]*tp[4]+e[5]*tp[5];
  __syncthreads();
  float u = 0.f;
  const float* pw = pred_W + (size_t)hth * HH;
  for (int d = 0; d < HH; ++d) u += te[d] * pw[d];
  hp[hth] = u;
  __syncthreads();
  float w = fus_b1[hth];
  const float* f1 = fus_W1 + (size_t)hth * 256 + 128;
  for (int d = 0; d < HH; ++d) w += hp[d] * f1[d];
  hp1[b * HH + hth] = w;
}

// last LN + gelu(L@fus_W1[:, :128]^T + hp1) @ fus_W2^T + fus_b2 -> logits. 4-row tiles.
__global__ __launch_bounds__(128) void final_fused(
    const float* __restrict__ S, const float* __restrict__ lng, const float* __restrict__ lnb,
    const float* __restrict__ fus_W1, const float* __restrict__ HP1,
    const float* __restrict__ fus_W2, const float* __restrict__ fus_b2,
    const float* __restrict__ item_emb, const int* __restrict__ pos,
    const int* __restrict__ neg, float* __restrict__ out) {
  int m0 = blockIdx.x * 4;
  int bidx = m0 >> 8;
  int n = threadIdx.x;
  __shared__ float Xt[4][132];
  __shared__ float Ht[4][132];
  __shared__ float Ft[4][132];
  __shared__ float mu[4], rs[4];
  #pragma unroll
  for (int r = 0; r < 4; ++r) Xt[r][n] = S[(size_t)(m0 + r) * HH + n];
  __syncthreads();
  if (n < 32) {
    int r = n >> 3, sg = n & 7;
    float s = 0.f;
    #pragma unroll
    for (int i = 0; i < 16; ++i) s += Xt[r][sg * 16 + i];
    s += __shfl_xor(s, 1); s += __shfl_xor(s, 2); s += __shfl_xor(s, 4);
    if (sg == 0) mu[r] = s * (1.0f / HH);
  }
  __syncthreads();
  if (n < 32) {
    int r = n >> 3, sg = n & 7;
    float mm = mu[r], s = 0.f;
    #pragma unroll
    for (int i = 0; i < 16; ++i) { float d = Xt[r][sg*16+i] - mm; s += d * d; }
    s += __shfl_xor(s, 1); s += __shfl_xor(s, 2); s += __shfl_xor(s, 4);
    if (sg == 0) rs[r] = rsqrtf(s * (1.0f / HH) + 1e-8f);
  }
  __syncthreads();
  float gg = lng[n], bb = lnb[n];
  #pragma unroll
  for (int r = 0; r < 4; ++r) Xt[r][n] = (Xt[r][n] - mu[r]) * rs[r] * gg + bb;
  __syncthreads();
  float acc[4] = {0.f, 0.f, 0.f, 0.f};
  const float* wr = fus_W1 + (size_t)n * 256;
  for (int d = 0; d < HH; d += 4) {
    float4 w = *(const float4*)(wr + d);
    #pragma unroll
    for (int r = 0; r < 4; ++r) {
      float4 a = *(const float4*)(&Xt[r][d]);
      acc[r] = fmaf(a.x, w.x, fmaf(a.y, w.y, fmaf(a.z, w.z, fmaf(a.w, w.w, acc[r]))));
    }
  }
  float hp = HP1[bidx * HH + n];
  #pragma unroll
  for (int r = 0; r < 4; ++r) {
    float v = acc[r] + hp;
    Ht[r][n] = 0.5f * v * (1.0f + erff(v * 0.70710678118654752f));
  }
  __syncthreads();
  float acc2[4] = {0.f, 0.f, 0.f, 0.f};
  wr = fus_W2 + (size_t)n * HH;
  for (int d = 0; d < HH; d += 4) {
    float4 w = *(const float4*)(wr + d);
    #pragma unroll
    for (int r = 0; r < 4; ++r) {
      float4 a = *(const float4*)(&Ht[r][d]);
      acc2[r] = fmaf(a.x, w.x, fmaf(a.y, w.y, fmaf(a.z, w.z, fmaf(a.w, w.w, acc2[r]))));
    }
  }
  float b2n = fus_b2[n];
  #pragma unroll
  for (int r = 0; r < 4; ++r) Ft[r][n] = acc2[r] + b2n;
  __syncthreads();
  if (n < 64) {
    int task = n >> 3;     // 0..7: r = task&3, which = task>>2
    int sg = n & 7;
    int r = task & 3;
    int w = task >> 2;
    int mrow = m0 + r;
    int idx = (w == 0) ? pos[mrow] : neg[mrow];
    const float* ie = item_emb + (size_t)idx * HH;
    float s = 0.f;
    #pragma unroll
    for (int i = 0; i < 16; ++i) s += Ft[r][sg * 16 + i] * ie[sg * 16 + i];
    s += __shfl_xor(s, 1); s += __shfl_xor(s, 2); s += __shfl_xor(s, 4);
    if (sg == 0) out[w * 2048 + mrow] = s;
  }
}

extern "C" void kernel_launch(void* const* d_in, const int* in_sizes, int n_in,
                              void* d_out, int out_size, void* d_ws, size_t ws_size,
                              hipStream_t stream) {
  const int*   log_seqs   = (const int*)d_in[0];
  const int*   tmat       = (const int*)d_in[1];
  const float* time_seq   = (const float*)d_in[2];
  const int*   pos_seqs   = (const int*)d_in[3];
  const int*   neg_seqs   = (const int*)d_in[4];
  const float* target_t   = (const float*)d_in[5];
  const float* item_emb   = (const float*)d_in[6];
  const float* abs_pos_K  = (const float*)d_in[7];
  const float* abs_pos_V  = (const float*)d_in[8];
  const float* time_K_emb = (const float*)d_in[9];
  const float* time_V_emb = (const float*)d_in[10];
  const float* Wq = (const float*)d_in[11];
  const float* bq = (const float*)d_in[12];
  const float* Wk = (const float*)d_in[13];
  const float* bk = (const float*)d_in[14];
  const float* Wv = (const float*)d_in[15];
  const float* bv = (const float*)d_in[16];
  const float* attn_ln_g = (const float*)d_in[17];
  const float* attn_ln_b = (const float*)d_in[18];
  const float* fwd_ln_g = (const float*)d_in[19];
  const float* fwd_ln_b = (const float*)d_in[20];
  const float* w1 = (const float*)d_in[21];
  const float* b1 = (const float*)d_in[22];
  const float* w2 = (const float*)d_in[23];
  const float* b2 = (const float*)d_in[24];
  const float* last_ln_g = (const float*)d_in[25];
  const float* last_ln_b = (const float*)d_in[26];
  const float* time_proj = (const float*)d_in[27];
  const float* lambdas = (const float*)d_in[28];
  const float* pred_W = (const float*)d_in[29];
  const float* fus_W1 = (const float*)d_in[30];
  const float* fus_b1 = (const float*)d_in[31];
  const float* fus_W2 = (const float*)d_in[32];
  const float* fus_b2 = (const float*)d_in[33];
  (void)in_sizes; (void)n_in; (void)out_size; (void)ws_size;

  float* out = (float*)d_out;
  float* ws = (float*)d_ws;
  const int M = 8 * TT;  // 2048
  float* SC6  = ws;                 // M*6
  float* SEQS = SC6 + M * 6;
  float* QN   = SEQS + M * HH;
  float* QB   = QN + M * HH;
  float* KT   = QB + M * HH;        // [b][h][d][t]
  float* VB   = KT + M * HH;
  float* HP1  = VB + M * HH;        // 8*128
  float* SCB  = HP1 + 8 * HH;       // 16*256*256 f32 = 4 MB

  embed_kernel<<<M, HH, 0, stream>>>(log_seqs, time_seq, item_emb, time_proj, SEQS, SC6);
  for (int l = 0; l < 2; ++l) {
    const size_t wo = (size_t)l * HH * HH;
    const size_t bo = (size_t)l * HH;
    qkv_fused<<<768, 128, 0, stream>>>(SEQS, Wq + wo, bq + bo, Wk + wo, bk + bo,
                                       Wv + wo, bv + bo, attn_ln_g + bo, attn_ln_b + bo,
                                       abs_pos_K, abs_pos_V, QN, QB, KT, VB);
    pkscb_kernel<<<1024, 256, 0, stream>>>(QB, time_K_emb, tmat, log_seqs, SC6, lambdas, SCB);
    attn_fused<<<2048, 256, 0, stream>>>(QB, KT, VB, QN, SCB, tmat, time_V_emb, SEQS);
    ffn_fused<<<512, 128, 0, stream>>>(SEQS, w1 + wo, b1 + bo, w2 + wo, b2 + bo,
                                       fwd_ln_g + bo, fwd_ln_b + bo, log_seqs, SEQS);
  }
  hper_kernel<<<8, 128, 0, stream>>>(target_t, time_proj, pred_W, fus_W1, fus_b1, HP1);
  final_fused<<<512, 128, 0, stream>>>(SEQS, last_ln_g, last_ln_b, fus_W1, HP1,
                                       fus_W2, fus_b2, item_emb, pos_seqs, neg_seqs, out);
}